// Round 4
// baseline (414.783 us; speedup 1.0000x reference)
//
#include <hip/hip_runtime.h>
#include <math.h>

#ifndef M_PI
#define M_PI 3.14159265358979323846
#endif

#define T_LEN 4096
#define M_LEN 2048   // T/2, complex FFT length
#define NFREQ 2049   // T/2 + 1
#define KM 8         // modes
#define LI 8         // iterations
#define CD 16        // channels

// ---------------- complex helpers ----------------
__device__ __forceinline__ float2 cadd(float2 a, float2 b){ return make_float2(a.x+b.x, a.y+b.y); }
__device__ __forceinline__ float2 csub(float2 a, float2 b){ return make_float2(a.x-b.x, a.y-b.y); }
__device__ __forceinline__ float2 cmul(float2 a, float2 b){ return make_float2(a.x*b.x - a.y*b.y, a.x*b.y + a.y*b.x); }
__device__ __forceinline__ float2 muli(float2 a){ return make_float2(-a.y, a.x); }          // * i  (inverse sign)
#define RC 0.70710678118654752440f
__device__ __forceinline__ float2 mulw81(float2 a){ return make_float2(RC*(a.x-a.y), RC*(a.x+a.y)); }   // * ( c+ic)
__device__ __forceinline__ float2 mulw83(float2 a){ return make_float2(-RC*(a.x+a.y), RC*(a.x-a.y)); }  // * (-c+ic)

// LDS XOR swizzle on float2 index: stockham radix-8 writes are stride-8/64
// float2 (16/8-way bank conflicts unswizzled); XOR bits4-7 into bits0-3 makes
// every access pattern in this kernel (fill, r8 reads/writes, r4, readout)
// land on >=16 distinct bank-pairs per wave.
#define SWZ(i) ((i) ^ (((i) >> 4) & 15))

// 8-point DFT, inverse sign (e^{+2πi nk/8}), natural-order in/out.
__device__ __forceinline__ void dft8_inv(const float2 a[8], float2 x[8]) {
    float2 s0=cadd(a[0],a[4]), s1=cadd(a[1],a[5]), s2=cadd(a[2],a[6]), s3=cadd(a[3],a[7]);
    float2 d0=csub(a[0],a[4]), d1=csub(a[1],a[5]), d2=csub(a[2],a[6]), d3=csub(a[3],a[7]);
    d1 = mulw81(d1); d2 = muli(d2); d3 = mulw83(d3);
    float2 e0=cadd(s0,s2), e2=csub(s0,s2), e1=cadd(s1,s3), e3=muli(csub(s1,s3));
    float2 f0=cadd(d0,d2), f2=csub(d0,d2), f1=cadd(d1,d3), f3=muli(csub(d1,d3));
    x[0]=cadd(e0,e1); x[4]=csub(e0,e1); x[2]=cadd(e2,e3); x[6]=csub(e2,e3);
    x[1]=cadd(f0,f1); x[5]=csub(f0,f1); x[3]=cadd(f2,f3); x[7]=csub(f2,f3);
}

// One Stockham radix-8 stage (inverse), in-place via regs + 2 barriers.
// Reads S[i + k*256], writes S[(i%m) + (8*(i/m)+k)*m], twiddle W_2048^{+k*j*m}.
template<int MSTAGE>
__device__ __forceinline__ void r8_stage(float2* S, int lt) {
    float2 a[8];
    #pragma unroll
    for (int k = 0; k < 8; ++k) a[k] = S[SWZ(lt + 256*k)];
    __syncthreads();
    float2 x[8];
    dft8_inv(a, x);
    const int j = lt / MSTAGE;
    const int r = lt % MSTAGE;
    float th = ((float)M_PI / 1024.0f) * (float)(j * MSTAGE);   // +2π*(j*m)/2048
    float swv, cwv; __sincosf(th, &swv, &cwv);
    float2 w1 = make_float2(cwv, swv);
    float2 w2 = cmul(w1,w1), w3 = cmul(w2,w1), w4 = cmul(w2,w2);
    float2 w5 = cmul(w3,w2), w6 = cmul(w3,w3), w7 = cmul(w4,w3);
    x[1]=cmul(x[1],w1); x[2]=cmul(x[2],w2); x[3]=cmul(x[3],w3);
    x[4]=cmul(x[4],w4); x[5]=cmul(x[5],w5); x[6]=cmul(x[6],w6); x[7]=cmul(x[7],w7);
    const int base = r + 8*MSTAGE*j;
    #pragma unroll
    for (int k = 0; k < 8; ++k) S[SWZ(base + MSTAGE*k)] = x[k];
    __syncthreads();
}

// Final radix-4 stage (m=512, j=0 -> no twiddle), 2 butterflies/thread, in place.
__device__ __forceinline__ void r4_stage_pair(float2* S, int lt) {
    float2 b[2][4];
    #pragma unroll
    for (int h = 0; h < 2; ++h) {
        int i2 = lt + 256*h;
        #pragma unroll
        for (int k = 0; k < 4; ++k) b[h][k] = S[SWZ(i2 + 512*k)];
    }
    __syncthreads();
    #pragma unroll
    for (int h = 0; h < 2; ++h) {
        int i2 = lt + 256*h;
        float2 s02=cadd(b[h][0],b[h][2]), d02=csub(b[h][0],b[h][2]);
        float2 s13=cadd(b[h][1],b[h][3]), d13=muli(csub(b[h][1],b[h][3]));
        S[SWZ(i2 +    0)] = cadd(s02,s13);
        S[SWZ(i2 +  512)] = cadd(d02,d13);
        S[SWZ(i2 + 1024)] = csub(s02,s13);
        S[SWZ(i2 + 1536)] = csub(d02,d13);
    }
    __syncthreads();
}

// Stockham radix-2 DIF, N=2048 (kept for k_fwd_iter).
template <int NT>
__device__ __forceinline__ float2* fft2048(float2* a, float2* b, int tid, float sign) {
    float2* src = a;
    float2* dst = b;
    int l = 1024;
    #pragma unroll 1
    for (int s = 0; s < 11; ++s) {
        float piol = sign * (float)M_PI / (float)l;
        #pragma unroll
        for (int ii = 0; ii < 1024 / NT; ++ii) {
            int i = tid + ii * NT;
            int j = i >> s;
            float2 A = src[i];
            float2 B = src[i + 1024];
            float ang = piol * (float)j;
            float sw, cw;
            __sincosf(ang, &sw, &cw);
            float2 sum = make_float2(A.x + B.x, A.y + B.y);
            float2 dif = make_float2(A.x - B.x, A.y - B.y);
            float2 tw = make_float2(dif.x * cw - dif.y * sw, dif.x * sw + dif.y * cw);
            int p = i + (j << s);
            dst[p] = sum;
            dst[p + (1 << s)] = tw;
        }
        __syncthreads();
        float2* t = src; src = dst; dst = t;
        l >>= 1;
    }
    return src;
}

// K1: one block per row (b,c). Forward rfft + L x K Jacobi iteration per bin.
// (UNCHANGED this round; radix-8 port next round once the engine validates.)
__global__ void __launch_bounds__(512)
k_fwd_iter(const float* __restrict__ x,
           const float* __restrict__ log_alpha,
           const float* __restrict__ raw_tau,
           const float* __restrict__ raw_omega,
           float2* __restrict__ u_ws)
{
    __shared__ float2 bufA[M_LEN];
    __shared__ float2 bufB[M_LEN];
    __shared__ float s_2a[LI * KM];
    __shared__ float s_tau[LI];
    __shared__ float s_om[KM];

    const int tid = threadIdx.x;
    const int row = blockIdx.x;
    const int b = row >> 4;
    const int c = row & 15;

    if (tid < LI * KM) s_2a[tid] = 2.0f * __expf(log_alpha[tid]);
    if (tid < LI)      s_tau[tid] = log1pf(__expf(raw_tau[tid]));
    if (tid < KM)      s_om[tid]  = 0.5f / (1.0f + __expf(-raw_omega[tid]));

    const float* xr = x + (size_t)b * T_LEN * CD + c;
    #pragma unroll
    for (int q = 0; q < 4; ++q) {
        int n = tid + q * 512;
        float e = xr[(size_t)(2 * n) * CD];
        float o = xr[(size_t)(2 * n + 1) * CD];
        bufA[n] = make_float2(e, o);
    }
    __syncthreads();

    float2* Z = fft2048<512>(bufA, bufB, tid, -1.0f);

    const size_t sb = (size_t)(b * (KM * CD) + c);

    for (int f = tid; f < NFREQ; f += 512) {
        float2 Zk = Z[f & (M_LEN - 1)];
        float2 Zm = Z[(M_LEN - f) & (M_LEN - 1)];
        float2 E = make_float2(0.5f * (Zk.x + Zm.x), 0.5f * (Zk.y - Zm.y));
        float2 D = make_float2(0.5f * (Zk.x - Zm.x), 0.5f * (Zk.y + Zm.y));
        float2 O = make_float2(D.y, -D.x);
        float ang = -2.0f * (float)M_PI * (float)f / (float)T_LEN;
        float sw, cw;
        __sincosf(ang, &sw, &cw);
        float fhx = E.x + cw * O.x - sw * O.y;
        float fhy = E.y + cw * O.y + sw * O.x;

        float freq = (float)f * (0.5f / (float)M_LEN);
        float dd[KM];
        #pragma unroll
        for (int k = 0; k < KM; ++k) {
            float d = freq - s_om[k];
            dd[k] = d * d;
        }

        float2 u[KM];
        #pragma unroll
        for (int k = 0; k < KM; ++k) u[k] = make_float2(0.f, 0.f);
        float lamx = 0.f, lamy = 0.f;

        #pragma unroll
        for (int l = 0; l < LI; ++l) {
            float usx = 0.f, usy = 0.f;
            #pragma unroll
            for (int k = 0; k < KM; ++k) { usx += u[k].x; usy += u[k].y; }
            float bx = fhx - usx + 0.5f * lamx;
            float by = fhy - usy + 0.5f * lamy;
            float sx = 0.f, sy = 0.f;
            #pragma unroll
            for (int k = 0; k < KM; ++k) {
                float den = fmaf(s_2a[l * KM + k], dd[k], 1.0f);
                float r = __builtin_amdgcn_rcpf(den);
                float ux = (bx + u[k].x) * r;
                float uy = (by + u[k].y) * r;
                u[k].x = ux; u[k].y = uy;
                sx += ux; sy += uy;
            }
            lamx += s_tau[l] * (fhx - sx);
            lamy += s_tau[l] * (fhy - sy);
        }

        #pragma unroll
        for (int k = 0; k < KM; ++k) {
            u_ws[(sb + (size_t)k * CD) * NFREQ + f] = u[k];
        }
    }
}

// K2: one block per (b,k). 16 inverse rffts as 4 passes x 4 channels.
// Radix-8 Stockham (8*8*8*4): 4 LDS stages instead of 11, DFT8 in registers,
// in-place single buffer per channel (read->barrier->write->barrier),
// XOR-swizzled LDS, 1 sincos/thread/stage. Pass loop FULLY unrolled so
// val[] stays statically indexed (r2's unroll-1 spilled it to scratch:
// FETCH/WRITE +62/+117 MB).
__global__ void __launch_bounds__(1024)
k_inv(const float2* __restrict__ u_ws, float* __restrict__ out)
{
    __shared__ float2 S[4][M_LEN];    // 64 KB, swizzled indexing

    const int tid = threadIdx.x;
    const int g   = tid >> 8;         // channel slot 0..3
    const int lt  = tid & 255;        // index within channel
    const int bk  = blockIdx.x;       // b*8 + k

    float val[CD][4];                 // statically indexed only
    const float sc = 1.0f / (float)M_LEN;

    #pragma unroll
    for (int cp = 0; cp < 4; ++cp) {
        const int c0 = 4 * cp;
        const float2* sp = u_ws + (size_t)(bk * CD + c0 + g) * NFREQ;

        // ---- fill: irfft even/odd repack straight from global ----
        // thread produces S[j] and S[2048-j] from one conjugate-pair of loads.
        #pragma unroll
        for (int q = 0; q < 4; ++q) {
            int j = lt + 256 * q;
            float2 Xj = sp[j];
            float2 Xm = sp[M_LEN - j];          // j=0 -> Nyquist (2048)
            float Ex = 0.5f * (Xj.x + Xm.x), Ey = 0.5f * (Xj.y - Xm.y);
            float Dx = 0.5f * (Xj.x - Xm.x), Dy = 0.5f * (Xj.y + Xm.y);
            float ang = (2.0f * (float)M_PI / (float)T_LEN) * (float)j;
            float swv, cwv;
            __sincosf(ang, &swv, &cwv);
            float Ox = cwv * Dx - swv * Dy;
            float Oy = cwv * Dy + swv * Dx;
            S[g][SWZ(j)] = make_float2((Ex - Oy) * sc, (Ey + Ox) * sc);
            if (j > 0) {
                S[g][SWZ(M_LEN - j)] = make_float2((Ex + Oy) * sc, (Ox - Ey) * sc);
            } else {
                float2 Xq = sp[1024];
                S[g][SWZ(1024)] = make_float2(Xq.x * sc, -Xq.y * sc);
            }
        }
        __syncthreads();

        // ---- 2048 = 8 * 8 * 8 * 4 ----
        r8_stage<1>(S[g], lt);
        r8_stage<8>(S[g], lt);
        r8_stage<64>(S[g], lt);
        r4_stage_pair(S[g], lt);

        // ---- readout: thread owns complex positions 2*tid, 2*tid+1 of all 4 ch ----
        #pragma unroll
        for (int cc = 0; cc < 4; ++cc) {
            float2 z0 = S[cc][SWZ(2 * tid)];
            float2 z1 = S[cc][SWZ(2 * tid + 1)];
            val[c0 + cc][0] = z0.x;   // t = 4*tid + 0
            val[c0 + cc][1] = z0.y;   // t = 4*tid + 1
            val[c0 + cc][2] = z1.x;
            val[c0 + cc][3] = z1.y;
        }
        __syncthreads();              // before next pass's fill overwrites S
    }

    // Each thread owns out[b, k, 4*tid .. 4*tid+3, 0..15]: contiguous 256 B.
    float4* op = (float4*)(out + ((size_t)bk * T_LEN + (size_t)(4 * tid)) * CD);
    #pragma unroll
    for (int r = 0; r < 4; ++r) {
        #pragma unroll
        for (int g2 = 0; g2 < 4; ++g2) {
            op[r * 4 + g2] = make_float4(val[4 * g2 + 0][r], val[4 * g2 + 1][r],
                                         val[4 * g2 + 2][r], val[4 * g2 + 3][r]);
        }
    }
}

extern "C" void kernel_launch(void* const* d_in, const int* in_sizes, int n_in,
                              void* d_out, int out_size, void* d_ws, size_t ws_size,
                              hipStream_t stream) {
    const float* x         = (const float*)d_in[0];
    const float* log_alpha = (const float*)d_in[1];
    const float* raw_tau   = (const float*)d_in[2];
    const float* raw_omega = (const float*)d_in[3];
    float* out = (float*)d_out;
    float2* u_ws = (float2*)d_ws;   // needs 8192 * 2049 * 8 B = 134.3 MB

    k_fwd_iter<<<dim3(64 * CD), dim3(512), 0, stream>>>(x, log_alpha, raw_tau,
                                                        raw_omega, u_ws);
    k_inv<<<dim3(64 * KM), dim3(1024), 0, stream>>>(u_ws, out);
}